// Round 12
// baseline (3426.208 us; speedup 1.0000x reference)
//
#include <hip/hip_runtime.h>

#define S_LEN 512
#define BATCH 64
#define EDIM  128
#define HDIM  256
#define GDIM  1024   // 4*H
#define TDIM  64
#define NROW  32768  // S*B
#define HSTR  264    // hb row stride in shorts

typedef __attribute__((ext_vector_type(8))) short short8;
typedef __attribute__((ext_vector_type(4))) short short4v;
typedef __attribute__((ext_vector_type(4))) unsigned short us4;
typedef __attribute__((ext_vector_type(4))) float f32x4;

__device__ __forceinline__ unsigned short f2bf(float f) {
  unsigned u = __float_as_uint(f);
  u += 0x7FFFu + ((u >> 16) & 1u);   // RNE
  return (unsigned short)(u >> 16);
}
__device__ __forceinline__ float bf2f(unsigned short h) {
  return __uint_as_float(((unsigned)h) << 16);
}
__device__ __forceinline__ float sigm(float x) {
  float e = __expf(-x);
  return __builtin_amdgcn_rcpf(1.f + e);
}
__device__ __forceinline__ float tanh_(float x) {
  float e = __expf(2.f * x);
  return 1.f - 2.f * __builtin_amdgcn_rcpf(e + 1.f);
}

// ---------------- Kernel 0: pack W_hh into MFMA-fragment order (bf16) ------
// frag id = (((dir*8 + w)*8 + kk)*8 + gi), gi = gt*2+ct.
// lane l: 8 bf16 = W[gt*256 + w*32 + ct*16 + cl][kk*32 + q*8 .. +7]
__global__ __launch_bounds__(256) void k_pack(
    const float* __restrict__ Whf, const float* __restrict__ Whb,
    unsigned short* __restrict__ wpk) {
  const int fid = blockIdx.x * 256 + threadIdx.x;   // 65536 lane-frags
  const int l = fid & 63;
  int rest = fid >> 6;
  const int gi = rest & 7;  rest >>= 3;
  const int kk = rest & 7;  rest >>= 3;
  const int w  = rest & 7;
  const int dir = rest >> 3;
  const int gt = gi >> 1, ct = gi & 1;
  const int q = l >> 4, cl = l & 15;
  const float* Wh = dir ? Whb : Whf;
  const int row = gt * 256 + w * 32 + ct * 16 + cl;
  const float* src = Wh + (size_t)row * HDIM + kk * 32 + q * 8;
  float4 v0 = *(const float4*)src;
  float4 v1 = *(const float4*)(src + 4);
  short8 t8;
  t8[0] = (short)f2bf(v0.x); t8[1] = (short)f2bf(v0.y);
  t8[2] = (short)f2bf(v0.z); t8[3] = (short)f2bf(v0.w);
  t8[4] = (short)f2bf(v1.x); t8[5] = (short)f2bf(v1.y);
  t8[6] = (short)f2bf(v1.z); t8[7] = (short)f2bf(v1.w);
  *(short8*)(wpk + (size_t)fid * 8) = t8;
}

// ---------------- Kernel 1: gather + input projection (both directions) ----
// xqT layout: [s][gatecol(1024)][batch(64)] bf16.
__global__ __launch_bounds__(512) void k_proj(
    const int* __restrict__ tok, const float* __restrict__ emb,
    const float* __restrict__ Wf, const float* __restrict__ bihf, const float* __restrict__ bhhf,
    const float* __restrict__ Wb, const float* __restrict__ bihb, const float* __restrict__ bhhb,
    unsigned short* __restrict__ xqf, unsigned short* __restrict__ xqb) {
  __shared__ short xt[256 * 136];
  const int tid = threadIdx.x;
  const int rowbase = blockIdx.x * 256;
  const int dir = blockIdx.y;
  const float* W  = dir ? Wb   : Wf;
  const float* bi = dir ? bihb : bihf;
  const float* bh = dir ? bhhb : bhhf;
  unsigned short* xq = dir ? xqb : xqf;

  for (int i = tid; i < 256 * 32; i += 512) {
    int row = i >> 5, c4 = (i & 31) << 2;
    int t = tok[rowbase + row];
    float4 v = *(const float4*)(emb + (size_t)t * EDIM + c4);
    short4v p;
    p.x = (short)f2bf(v.x); p.y = (short)f2bf(v.y);
    p.z = (short)f2bf(v.z); p.w = (short)f2bf(v.w);
    *(short4v*)&xt[row * 136 + c4] = p;
  }
  __syncthreads();

  const int w = tid >> 6, l = tid & 63, q = l >> 4, cl = l & 15;

  short8 a[2][4];
#pragma unroll
  for (int rt = 0; rt < 2; ++rt)
#pragma unroll
    for (int kk = 0; kk < 4; ++kk)
      a[rt][kk] = *(const short8*)&xt[((2 * w + rt) * 16 + cl) * 136 + kk * 32 + q * 8];

  for (int ct = 0; ct < 64; ++ct) {
    const int colg = ct * 16 + cl;
    short8 bw[4];
#pragma unroll
    for (int kk = 0; kk < 4; ++kk) {
      const float* wp = W + (size_t)colg * EDIM + kk * 32 + q * 8;
      float4 w0 = *(const float4*)wp;
      float4 w1 = *(const float4*)(wp + 4);
      short8 t8;
      t8[0] = (short)f2bf(w0.x); t8[1] = (short)f2bf(w0.y);
      t8[2] = (short)f2bf(w0.z); t8[3] = (short)f2bf(w0.w);
      t8[4] = (short)f2bf(w1.x); t8[5] = (short)f2bf(w1.y);
      t8[6] = (short)f2bf(w1.z); t8[7] = (short)f2bf(w1.w);
      bw[kk] = t8;
    }
    float bias = bi[colg] + bh[colg];
#pragma unroll
    for (int rt = 0; rt < 2; ++rt) {
      f32x4 acc = {bias, bias, bias, bias};
#pragma unroll
      for (int kk = 0; kk < 4; ++kk)
        acc = __builtin_amdgcn_mfma_f32_16x16x32_bf16(a[rt][kk], bw[kk], acc, 0, 0, 0);
      const int rowg = rowbase + (2 * w + rt) * 16 + q * 4;
      const int s = rowg >> 6, b0 = rowg & 63;
      us4 p;
      p[0] = f2bf(acc[0]); p[1] = f2bf(acc[1]);
      p[2] = f2bf(acc[2]); p[3] = f2bf(acc[3]);
      *(us4*)&xq[((size_t)s * GDIM + colg) * BATCH + b0] = p;
    }
  }
}

// ---------------- Kernel 2: LSTM scans -------------------------------------
// grid = 8: dir = bx&1, 16-row bgroup = bx>>1. 512 threads = 8 waves, 2/SIMD.
// W per wave (8 kk-groups x 8 frags = 64KB):
//   kk0-3 -> AGPRs (128 AGPRs/wave, inline-asm MFMA with "a" B-operand;
//            the VGPR_Count=256 ceiling never touched this half of the file)
//   kk4-5 -> LDS-resident (128KB)
//   kk6-7 -> streamed from L2 (128KB/CU/step) through ONE rolling 32-reg slot.
__global__ __launch_bounds__(512, 1) __attribute__((amdgpu_waves_per_eu(2, 2)))
void k_lstm(
    const unsigned short* __restrict__ wpk,
    const unsigned short* __restrict__ xqf, const unsigned short* __restrict__ xqb,
    unsigned short* __restrict__ hq) {
  __shared__ char wsl[131072];              // 8 waves x 2 kk-groups x 8 frags x 1KB
  __shared__ short hb0[16][HSTR];
  __shared__ short hb1[16][HSTR];
  const int tid = threadIdx.x;
  const int dir = blockIdx.x & 1, bg = blockIdx.x >> 1;
  const int w = tid >> 6, l = tid & 63, q = l >> 4, cl = l & 15;
  const int brow = bg * 16 + q * 4;         // this lane's 4 batch rows
  const char* xqB = (const char*)(dir ? xqb : xqf);
  const char* wlp = (const char*)wpk + (size_t)(dir * 8 + w) * 65536 + l * 16;
  char* wslw = wsl + w * 16384;

  for (int i = tid; i < 16 * HSTR; i += 512) { ((short*)hb0)[i] = 0; ((short*)hb1)[i] = 0; }

  // stage kk4,kk5 into LDS once (async DMA, lane-linear dest)
#pragma unroll
  for (int kr = 0; kr < 2; ++kr)
#pragma unroll
    for (int gi = 0; gi < 8; ++gi)
      __builtin_amdgcn_global_load_lds(
          (const unsigned int*)(wlp + ((4 + kr) * 8 + gi) * 1024),
          (unsigned int*)(wslw + (kr * 8 + gi) * 1024), 16, 0, 0);

#define LOADG(DST, KK)                                                        \
    _Pragma("unroll") for (int gi = 0; gi < 8; ++gi)                          \
      DST[gi] = *(const short8*)(wlp + ((KK) * 8 + gi) * 1024);
#define MF1(AV, WV, GI)                                                       \
    acc[GI] = __builtin_amdgcn_mfma_f32_16x16x32_bf16(AV, WV, acc[GI], 0, 0, 0);
#define MFG(AV, WV)                                                           \
    _Pragma("unroll") for (int gi = 0; gi < 8; ++gi)                          \
      acc[gi] = __builtin_amdgcn_mfma_f32_16x16x32_bf16(AV, WV[gi], acc[gi], 0, 0, 0);
// AGPR-resident W group: B operand read straight from AGPRs
#define MFA(AV, WG)                                                           \
    _Pragma("unroll") for (int gi = 0; gi < 8; ++gi)                          \
      asm("v_mfma_f32_16x16x32_bf16 %0, %1, %2, %0"                           \
          : "+v"(acc[gi]) : "v"(AV), "a"(WG[gi]));
// LDS-resident W group KR (kk4+KR): 8 frags, rolled 2-deep
#define MFLDS(AV, KR) {                                                       \
    short8 wlA = *(const short8*)(wslw + ((KR) * 8 + 0) * 1024 + l * 16);     \
    short8 wlB = *(const short8*)(wslw + ((KR) * 8 + 1) * 1024 + l * 16);     \
    MF1(AV, wlA, 0)                                                           \
    wlA = *(const short8*)(wslw + ((KR) * 8 + 2) * 1024 + l * 16);            \
    MF1(AV, wlB, 1)                                                           \
    wlB = *(const short8*)(wslw + ((KR) * 8 + 3) * 1024 + l * 16);            \
    MF1(AV, wlA, 2)                                                           \
    wlA = *(const short8*)(wslw + ((KR) * 8 + 4) * 1024 + l * 16);            \
    MF1(AV, wlB, 3)                                                           \
    wlB = *(const short8*)(wslw + ((KR) * 8 + 5) * 1024 + l * 16);            \
    MF1(AV, wlA, 4)                                                           \
    wlA = *(const short8*)(wslw + ((KR) * 8 + 6) * 1024 + l * 16);            \
    MF1(AV, wlB, 5)                                                           \
    wlB = *(const short8*)(wslw + ((KR) * 8 + 7) * 1024 + l * 16);            \
    MF1(AV, wlA, 6)                                                           \
    MF1(AV, wlB, 7)                                                           \
  }

  // AGPR-stationary kk0-3: 32 frags = 128 AGPRs, loaded exactly once
  short8 wag0[8], wag1[8], wag2[8], wag3[8];
  LOADG(wag0, 0)
  LOADG(wag1, 1)
  LOADG(wag2, 2)
  LOADG(wag3, 3)

  // per-lane xq byte offsets for the 8 (gt,ct) gate cols
  int xlane[8];
#pragma unroll
  for (int gi = 0; gi < 8; ++gi) {
    const int gt = gi >> 1, ct = gi & 1;
    xlane[gi] = ((gt * 256 + w * 32 + ct * 16 + cl) * BATCH + brow) * 2;
  }
  const int hq_lb0 = (brow * 512 + dir * 256 + w * 32 + cl) * 2;       // ct=0
  const int hq_lb1 = hq_lb0 + 32;                                      // ct=1

  const int sd  = dir ? -(GDIM * BATCH * 2) : (GDIM * BATCH * 2);
  const int hsd = dir ? -(BATCH * 512 * 2)  : (BATCH * 512 * 2);
  const int s0 = dir ? (S_LEN - 1) : 0;
  int xoff    = s0 * (GDIM * BATCH * 2);
  int hq_soff = s0 * (BATCH * 512 * 2);

  // step-0 xp prefetch (full-flight across the prologue barrier)
  us4 xp[8];
#pragma unroll
  for (int gi = 0; gi < 8; ++gi)
    xp[gi] = *(const us4*)(xqB + xoff + xlane[gi]);
  xoff += sd;

  float cst[8] = {0.f, 0.f, 0.f, 0.f, 0.f, 0.f, 0.f, 0.f};
  __syncthreads();   // drains prologue DMAs + hbuf zeroing

#define STEP_BODY(RB, WB, T) {                                               \
    short8 sA[8];                                                            \
    LOADG(sA, 6)                        /* streamed kk6: ~48 MFMAs flight */ \
    f32x4 acc[8];                                                            \
    const f32x4 zz = {0.f, 0.f, 0.f, 0.f};                                   \
    _Pragma("unroll") for (int gi = 0; gi < 8; ++gi) acc[gi] = zz;           \
    short8 av;                                                               \
    av = *(const short8*)&RB[cl][0 * 32 + q * 8];  MFA(av, wag0)             \
    av = *(const short8*)&RB[cl][1 * 32 + q * 8];  MFA(av, wag1)             \
    av = *(const short8*)&RB[cl][2 * 32 + q * 8];  MFA(av, wag2)             \
    av = *(const short8*)&RB[cl][3 * 32 + q * 8];  MFA(av, wag3)             \
    av = *(const short8*)&RB[cl][4 * 32 + q * 8];  MFLDS(av, 0)              \
    av = *(const short8*)&RB[cl][5 * 32 + q * 8];  MFLDS(av, 1)              \
    av = *(const short8*)&RB[cl][6 * 32 + q * 8];  MFG(av, sA)               \
    LOADG(sA, 7)                        /* streamed kk7 */                   \
    av = *(const short8*)&RB[cl][7 * 32 + q * 8];  MFG(av, sA)               \
    _Pragma("unroll") for (int ct = 0; ct < 2; ++ct)                         \
      _Pragma("unroll") for (int r = 0; r < 4; ++r) {                        \
        float gi_ = sigm(acc[0 + ct][r] + bf2f(xp[0 + ct][r]));              \
        float gf  = sigm(acc[2 + ct][r] + bf2f(xp[2 + ct][r]));              \
        float gg  = tanh_(acc[4 + ct][r] + bf2f(xp[4 + ct][r]));             \
        float go  = sigm(acc[6 + ct][r] + bf2f(xp[6 + ct][r]));              \
        float cn = gf * cst[ct * 4 + r] + gi_ * gg;                          \
        cst[ct * 4 + r] = cn;                                                \
        unsigned short hbv = f2bf(go * tanh_(cn));                           \
        WB[q * 4 + r][w * 32 + ct * 16 + cl] = (short)hbv;                   \
        *(unsigned short*)((char*)hq + hq_soff + (ct ? hq_lb1 : hq_lb0)      \
                           + r * 1024) = hbv;                                \
      }                                                                      \
    hq_soff += hsd;                                                          \
    _Pragma("unroll") for (int gi = 0; gi < 8; ++gi)                         \
      xp[gi] = *(const us4*)(xqB + xoff + xlane[gi]);                        \
    if ((T) < S_LEN - 2) xoff += sd;                                         \
    asm volatile("s_waitcnt lgkmcnt(0)\n\ts_barrier" ::: "memory");          \
  }

  for (int it = 0; it < S_LEN / 2; ++it) {
    const int t = 2 * it;
    STEP_BODY(hb0, hb1, t);
    STEP_BODY(hb1, hb0, t + 1);
  }
#undef STEP_BODY
#undef LOADG
#undef MF1
#undef MFG
#undef MFA
#undef MFLDS
}

// ---------------- Kernel 3: output projection ------------------------------
__global__ __launch_bounds__(256) void k_out(
    const unsigned short* __restrict__ hq, const float* __restrict__ Wo,
    const float* __restrict__ bo, float* __restrict__ out) {
  __shared__ short wlds[64 * 520];
  const int tid = threadIdx.x;
  for (int i = tid; i < 64 * 128; i += 256) {
    int row = i >> 7, c4 = (i & 127) << 2;
    float4 v = *(const float4*)(Wo + (size_t)row * 512 + c4);
    short4v p;
    p.x = (short)f2bf(v.x); p.y = (short)f2bf(v.y);
    p.z = (short)f2bf(v.z); p.w = (short)f2bf(v.w);
    *(short4v*)&wlds[row * 520 + c4] = p;
  }
  __syncthreads();

  const int w = tid >> 6, l = tid & 63, q = l >> 4, cl = l & 15;
  const int rtb = blockIdx.x * 64 + w * 16;

  short8 a[16];
#pragma unroll
  for (int kk = 0; kk < 16; ++kk)
    a[kk] = *(const short8*)&hq[(size_t)(rtb + cl) * 512 + kk * 32 + q * 8];

#pragma unroll
  for (int ct = 0; ct < 4; ++ct) {
    float bias = bo[ct * 16 + cl];
    f32x4 acc = {bias, bias, bias, bias};
#pragma unroll
    for (int kk = 0; kk < 16; ++kk) {
      short8 b = *(const short8*)&wlds[(ct * 16 + cl) * 520 + kk * 32 + q * 8];
      acc = __builtin_amdgcn_mfma_f32_16x16x32_bf16(a[kk], b, acc, 0, 0, 0);
    }
#pragma unroll
    for (int r = 0; r < 4; ++r)
      out[(size_t)(rtb + q * 4 + r) * TDIM + ct * 16 + cl] = acc[r];
  }
}

extern "C" void kernel_launch(void* const* d_in, const int* in_sizes, int n_in,
                              void* d_out, int out_size, void* d_ws, size_t ws_size,
                              hipStream_t stream) {
  const int*   tok  = (const int*)d_in[0];
  const float* emb  = (const float*)d_in[1];
  const float* Wihf = (const float*)d_in[2];
  const float* Whhf = (const float*)d_in[3];
  const float* bihf = (const float*)d_in[4];
  const float* bhhf = (const float*)d_in[5];
  const float* Wihb = (const float*)d_in[6];
  const float* Whhb = (const float*)d_in[7];
  const float* bihb = (const float*)d_in[8];
  const float* bhhb = (const float*)d_in[9];
  const float* Wo   = (const float*)d_in[10];
  const float* bo   = (const float*)d_in[11];
  float* out = (float*)d_out;

  char* ws = (char*)d_ws;
  unsigned short* xqf = (unsigned short*)ws;                                  // 64 MiB
  unsigned short* xqb = (unsigned short*)(ws + (size_t)NROW * GDIM * 2);      // 64 MiB
  unsigned short* hq  = (unsigned short*)(ws + (size_t)NROW * GDIM * 4);      // 32 MiB
  unsigned short* wpk = (unsigned short*)d_out;   // parked; k_out overwrites d_out later

  k_pack<<<256, 256, 0, stream>>>(Whhf, Whhb, wpk);
  k_proj<<<dim3(128, 2), 512, 0, stream>>>(tok, emb, Wihf, bihf, bhhf,
                                           Wihb, bihb, bhhb, xqf, xqb);
  k_lstm<<<8, 512, 0, stream>>>(wpk, xqf, xqb, hq);
  k_out<<<512, 256, 0, stream>>>(hq, Wo, bo, out);
}

// Round 14
// 1776.578 us; speedup vs baseline: 1.9285x; 1.9285x over previous
//
#include <hip/hip_runtime.h>

#define S_LEN 512
#define BATCH 64
#define EDIM  128
#define HDIM  256
#define GDIM  1024   // 4*H
#define TDIM  64
#define NROW  32768  // S*B
#define HSTR  264    // hb row stride in shorts

typedef __attribute__((ext_vector_type(8))) short short8;
typedef __attribute__((ext_vector_type(4))) short short4v;
typedef __attribute__((ext_vector_type(4))) unsigned short us4;
typedef __attribute__((ext_vector_type(4))) float f32x4;

__device__ __forceinline__ unsigned short f2bf(float f) {
  unsigned u = __float_as_uint(f);
  u += 0x7FFFu + ((u >> 16) & 1u);   // RNE
  return (unsigned short)(u >> 16);
}
__device__ __forceinline__ float bf2f(unsigned short h) {
  return __uint_as_float(((unsigned)h) << 16);
}
__device__ __forceinline__ float sigm(float x) {
  float e = __expf(-x);
  return __builtin_amdgcn_rcpf(1.f + e);
}
__device__ __forceinline__ float tanh_(float x) {
  float e = __expf(2.f * x);
  return 1.f - 2.f * __builtin_amdgcn_rcpf(e + 1.f);
}

// ---------------- Kernel 0: pack W_hh (4-way col-split frag order) + flags -
// frag id = ((((dir*4 + ch)*4 + w)*8 + kk)*4 + gi);  gi == gate (0..3).
// lane l: 8 bf16 = W[gi*256 + ch*64 + w*16 + cl][kk*32 + q*8 .. +7]
__global__ __launch_bounds__(256) void k_pack(
    const float* __restrict__ Whf, const float* __restrict__ Whb,
    unsigned short* __restrict__ wpk, int* __restrict__ flags) {
  const int fid = blockIdx.x * 256 + threadIdx.x;   // 65536 lane-frags
  const int l = fid & 63;
  int rest = fid >> 6;
  const int gi = rest & 3;  rest >>= 2;
  const int kk = rest & 7;  rest >>= 3;
  const int w  = rest & 3;  rest >>= 2;
  const int ch = rest & 3;  rest >>= 2;
  const int dir = rest;     // 0..1
  const int q = l >> 4, cl = l & 15;
  const float* Wh = dir ? Whb : Whf;
  const int row = gi * 256 + ch * 64 + w * 16 + cl;
  const float* src = Wh + (size_t)row * HDIM + kk * 32 + q * 8;
  float4 v0 = *(const float4*)src;
  float4 v1 = *(const float4*)(src + 4);
  short8 t8;
  t8[0] = (short)f2bf(v0.x); t8[1] = (short)f2bf(v0.y);
  t8[2] = (short)f2bf(v0.z); t8[3] = (short)f2bf(v0.w);
  t8[4] = (short)f2bf(v1.x); t8[5] = (short)f2bf(v1.y);
  t8[6] = (short)f2bf(v1.z); t8[7] = (short)f2bf(v1.w);
  *(short8*)(wpk + (size_t)fid * 8) = t8;
  // zero the sync flags every launch (stream-ordered before k_lstm)
  if (blockIdx.x == 0)
    for (int i = threadIdx.x; i < 512; i += 256) flags[i] = 0;
}

// ---------------- Kernel 1: gather + input projection (both directions) ----
// xqT layout: [s][gatecol(1024)][batch(64)] bf16.
__global__ __launch_bounds__(512) void k_proj(
    const int* __restrict__ tok, const float* __restrict__ emb,
    const float* __restrict__ Wf, const float* __restrict__ bihf, const float* __restrict__ bhhf,
    const float* __restrict__ Wb, const float* __restrict__ bihb, const float* __restrict__ bhhb,
    unsigned short* __restrict__ xqf, unsigned short* __restrict__ xqb) {
  __shared__ short xt[256 * 136];
  const int tid = threadIdx.x;
  const int rowbase = blockIdx.x * 256;
  const int dir = blockIdx.y;
  const float* W  = dir ? Wb   : Wf;
  const float* bi = dir ? bihb : bihf;
  const float* bh = dir ? bhhb : bhhf;
  unsigned short* xq = dir ? xqb : xqf;

  for (int i = tid; i < 256 * 32; i += 512) {
    int row = i >> 5, c4 = (i & 31) << 2;
    int t = tok[rowbase + row];
    float4 v = *(const float4*)(emb + (size_t)t * EDIM + c4);
    short4v p;
    p.x = (short)f2bf(v.x); p.y = (short)f2bf(v.y);
    p.z = (short)f2bf(v.z); p.w = (short)f2bf(v.w);
    *(short4v*)&xt[row * 136 + c4] = p;
  }
  __syncthreads();

  const int w = tid >> 6, l = tid & 63, q = l >> 4, cl = l & 15;

  short8 a[2][4];
#pragma unroll
  for (int rt = 0; rt < 2; ++rt)
#pragma unroll
    for (int kk = 0; kk < 4; ++kk)
      a[rt][kk] = *(const short8*)&xt[((2 * w + rt) * 16 + cl) * 136 + kk * 32 + q * 8];

  for (int ct = 0; ct < 64; ++ct) {
    const int colg = ct * 16 + cl;
    short8 bw[4];
#pragma unroll
    for (int kk = 0; kk < 4; ++kk) {
      const float* wp = W + (size_t)colg * EDIM + kk * 32 + q * 8;
      float4 w0 = *(const float4*)wp;
      float4 w1 = *(const float4*)(wp + 4);
      short8 t8;
      t8[0] = (short)f2bf(w0.x); t8[1] = (short)f2bf(w0.y);
      t8[2] = (short)f2bf(w0.z); t8[3] = (short)f2bf(w0.w);
      t8[4] = (short)f2bf(w1.x); t8[5] = (short)f2bf(w1.y);
      t8[6] = (short)f2bf(w1.z); t8[7] = (short)f2bf(w1.w);
      bw[kk] = t8;
    }
    float bias = bi[colg] + bh[colg];
#pragma unroll
    for (int rt = 0; rt < 2; ++rt) {
      f32x4 acc = {bias, bias, bias, bias};
#pragma unroll
      for (int kk = 0; kk < 4; ++kk)
        acc = __builtin_amdgcn_mfma_f32_16x16x32_bf16(a[rt][kk], bw[kk], acc, 0, 0, 0);
      const int rowg = rowbase + (2 * w + rt) * 16 + q * 4;
      const int s = rowg >> 6, b0 = rowg & 63;
      us4 p;
      p[0] = f2bf(acc[0]); p[1] = f2bf(acc[1]);
      p[2] = f2bf(acc[2]); p[3] = f2bf(acc[3]);
      *(us4*)&xq[((size_t)s * GDIM + colg) * BATCH + b0] = p;
    }
  }
}

// ---------------- Kernel 2: LSTM scans, 4-way col split --------------------
// grid = 32: bx = dir*16 + bg*4 + ch. 256 thr = 4 waves = 1/SIMD (256 VGPRs).
// Block owns 64 h-cols; W = 32KB/wave = 128 VGPRs, FULLY register-stationary.
// Per step: MFMA(K=256 from LDS hb) -> gates -> publish own h-quarter to
// parity-buffered global hx + release flag -> spin on 3 partners -> gather
// their quarters into hb_next. Flags zeroed each launch by k_pack.
// R14 fix: hx publish offset now includes the q row term (q*512).
__global__ __launch_bounds__(256, 1) __attribute__((amdgpu_waves_per_eu(1, 1)))
void k_lstm(
    const unsigned short* __restrict__ wpk,
    const unsigned short* __restrict__ xqf, const unsigned short* __restrict__ xqb,
    unsigned short* __restrict__ hq, unsigned short* __restrict__ hx,
    int* __restrict__ flags) {
  __shared__ short hb0[16][HSTR];
  __shared__ short hb1[16][HSTR];
  const int tid = threadIdx.x;
  const int bx = blockIdx.x;
  const int ch = bx & 3, bg = (bx >> 2) & 3, dir = bx >> 4;
  const int bxb = bx & ~3;
  const int w = tid >> 6, l = tid & 63, q = l >> 4, cl = l & 15;
  const int brow = bg * 16 + q * 4;
  const int hcol = ch * 64 + w * 16 + cl;       // this lane's h column (0..255)
  const char* xqB = (const char*)(dir ? xqb : xqf);
  const char* wlp = (const char*)wpk + (size_t)((dir * 4 + ch) * 4 + w) * 32768 + l * 16;
  char* hxB = (char*)hx;

  for (int i = tid; i < 16 * HSTR; i += 256) { ((short*)hb0)[i] = 0; ((short*)hb1)[i] = 0; }

  // W fully stationary: 8 kk x 4 gates = 32 frags = 128 VGPRs, loaded once
  short8 wst[8][4];
#pragma unroll
  for (int kk = 0; kk < 8; ++kk)
#pragma unroll
    for (int gi = 0; gi < 4; ++gi)
      wst[kk][gi] = *(const short8*)(wlp + (kk * 4 + gi) * 1024);

  int xlane[4];
#pragma unroll
  for (int gi = 0; gi < 4; ++gi)
    xlane[gi] = ((gi * 256 + hcol) * BATCH + brow) * 2;
  const int hq_lbyte = (brow * 512 + dir * 256 + hcol) * 2;

  const int sd  = dir ? -(GDIM * BATCH * 2) : (GDIM * BATCH * 2);
  const int hsd = dir ? -(BATCH * 512 * 2)  : (BATCH * 512 * 2);
  const int s0 = dir ? (S_LEN - 1) : 0;
  int xoff    = s0 * (GDIM * BATCH * 2);
  int hq_soff = s0 * (BATCH * 512 * 2);

  // hx: [par2][blk32][row16][col64] us.
  // own store: row = q*4+r -> byte q*512 + r*128; col = w*16+cl.
  const int hx_own  = bx * 2048 + q * 512 + (w * 16 + cl) * 2;   // +r*128 +par*65536
  const int hx_prow = (tid >> 4) * 128 + (tid & 15) * 8;         // partner gather

  us4 xp[4];
#pragma unroll
  for (int gi = 0; gi < 4; ++gi)
    xp[gi] = *(const us4*)(xqB + xoff + xlane[gi]);
  xoff += sd;

  float cst[4] = {0.f, 0.f, 0.f, 0.f};
  __syncthreads();

#define STEP4(RB, WB, PAR, T) {                                              \
    f32x4 acc[4];                                                            \
    const f32x4 zz = {0.f, 0.f, 0.f, 0.f};                                   \
    acc[0] = zz; acc[1] = zz; acc[2] = zz; acc[3] = zz;                      \
    _Pragma("unroll") for (int kk = 0; kk < 8; ++kk) {                       \
      short8 av = *(const short8*)&RB[cl][kk * 32 + q * 8];                  \
      _Pragma("unroll") for (int gi = 0; gi < 4; ++gi)                       \
        acc[gi] = __builtin_amdgcn_mfma_f32_16x16x32_bf16(av, wst[kk][gi], acc[gi], 0, 0, 0); \
    }                                                                        \
    _Pragma("unroll") for (int r = 0; r < 4; ++r) {                          \
      float gi_ = sigm(acc[0][r] + bf2f(xp[0][r]));                          \
      float gf  = sigm(acc[1][r] + bf2f(xp[1][r]));                          \
      float gg  = tanh_(acc[2][r] + bf2f(xp[2][r]));                         \
      float go  = sigm(acc[3][r] + bf2f(xp[3][r]));                          \
      float cn = gf * cst[r] + gi_ * gg;                                     \
      cst[r] = cn;                                                           \
      unsigned short hbv = f2bf(go * tanh_(cn));                             \
      WB[q * 4 + r][hcol] = (short)hbv;                                      \
      *(unsigned short*)(hxB + (PAR) * 65536 + hx_own + r * 128) = hbv;      \
      *(unsigned short*)((char*)hq + hq_soff + hq_lbyte + r * 1024) = hbv;   \
    }                                                                        \
    hq_soff += hsd;                                                          \
    asm volatile("s_waitcnt vmcnt(0)" ::: "memory");                         \
    __builtin_amdgcn_s_barrier();                                            \
    if (tid == 0)                                                            \
      __hip_atomic_store(&flags[bx * 16], (T) + 1, __ATOMIC_RELEASE,         \
                         __HIP_MEMORY_SCOPE_AGENT);                          \
    if (tid < 3) {                                                           \
      const int pc = (tid < ch) ? tid : tid + 1;                             \
      while (__hip_atomic_load(&flags[(bxb + pc) * 16], __ATOMIC_ACQUIRE,    \
                               __HIP_MEMORY_SCOPE_AGENT) < (T) + 1) {}       \
    }                                                                        \
    __builtin_amdgcn_s_barrier();                                            \
    _Pragma("unroll") for (int p = 0; p < 3; ++p) {                          \
      const int pc = (p < ch) ? p : p + 1;                                   \
      us4 ph = *(const us4*)(hxB + (PAR) * 65536 + (bxb + pc) * 2048 + hx_prow); \
      *(us4*)&WB[tid >> 4][pc * 64 + (tid & 15) * 4] = ph;                   \
    }                                                                        \
    _Pragma("unroll") for (int gi = 0; gi < 4; ++gi)                         \
      xp[gi] = *(const us4*)(xqB + xoff + xlane[gi]);                        \
    if ((T) < S_LEN - 2) xoff += sd;                                         \
    asm volatile("s_waitcnt lgkmcnt(0)\n\ts_barrier" ::: "memory");          \
  }

  for (int it = 0; it < S_LEN / 2; ++it) {
    const int t = 2 * it;
    STEP4(hb0, hb1, 0, t);
    STEP4(hb1, hb0, 1, t + 1);
  }
#undef STEP4
}

// ---------------- Kernel 3: output projection ------------------------------
__global__ __launch_bounds__(256) void k_out(
    const unsigned short* __restrict__ hq, const float* __restrict__ Wo,
    const float* __restrict__ bo, float* __restrict__ out) {
  __shared__ short wlds[64 * 520];
  const int tid = threadIdx.x;
  for (int i = tid; i < 64 * 128; i += 256) {
    int row = i >> 7, c4 = (i & 127) << 2;
    float4 v = *(const float4*)(Wo + (size_t)row * 512 + c4);
    short4v p;
    p.x = (short)f2bf(v.x); p.y = (short)f2bf(v.y);
    p.z = (short)f2bf(v.z); p.w = (short)f2bf(v.w);
    *(short4v*)&wlds[row * 520 + c4] = p;
  }
  __syncthreads();

  const int w = tid >> 6, l = tid & 63, q = l >> 4, cl = l & 15;
  const int rtb = blockIdx.x * 64 + w * 16;

  short8 a[16];
#pragma unroll
  for (int kk = 0; kk < 16; ++kk)
    a[kk] = *(const short8*)&hq[(size_t)(rtb + cl) * 512 + kk * 32 + q * 8];

#pragma unroll
  for (int ct = 0; ct < 4; ++ct) {
    float bias = bo[ct * 16 + cl];
    f32x4 acc = {bias, bias, bias, bias};
#pragma unroll
    for (int kk = 0; kk < 16; ++kk) {
      short8 b = *(const short8*)&wlds[(ct * 16 + cl) * 520 + kk * 32 + q * 8];
      acc = __builtin_amdgcn_mfma_f32_16x16x32_bf16(a[kk], b, acc, 0, 0, 0);
    }
#pragma unroll
    for (int r = 0; r < 4; ++r)
      out[(size_t)(rtb + q * 4 + r) * TDIM + ct * 16 + cl] = acc[r];
  }
}

extern "C" void kernel_launch(void* const* d_in, const int* in_sizes, int n_in,
                              void* d_out, int out_size, void* d_ws, size_t ws_size,
                              hipStream_t stream) {
  const int*   tok  = (const int*)d_in[0];
  const float* emb  = (const float*)d_in[1];
  const float* Wihf = (const float*)d_in[2];
  const float* Whhf = (const float*)d_in[3];
  const float* bihf = (const float*)d_in[4];
  const float* bhhf = (const float*)d_in[5];
  const float* Wihb = (const float*)d_in[6];
  const float* Whhb = (const float*)d_in[7];
  const float* bihb = (const float*)d_in[8];
  const float* bhhb = (const float*)d_in[9];
  const float* Wo   = (const float*)d_in[10];
  const float* bo   = (const float*)d_in[11];
  float* out = (float*)d_out;

  char* ws = (char*)d_ws;
  unsigned short* xqf = (unsigned short*)ws;                                  // 64 MiB
  unsigned short* xqb = (unsigned short*)(ws + (size_t)NROW * GDIM * 2);      // 64 MiB
  unsigned short* hq  = (unsigned short*)(ws + (size_t)NROW * GDIM * 4);      // 32 MiB
  // scratch parked inside d_out (k_out fully overwrites d_out afterwards):
  unsigned short* wpk   = (unsigned short*)d_out;                             // 1 MiB
  unsigned short* hx    = (unsigned short*)((char*)d_out + (2u << 20));       // 128 KiB
  int*            flags = (int*)((char*)d_out + (4u << 20));                  // 2 KiB

  k_pack<<<256, 256, 0, stream>>>(Whhf, Whhb, wpk, flags);
  k_proj<<<dim3(128, 2), 512, 0, stream>>>(tok, emb, Wihf, bihf, bhhf,
                                           Wihb, bihb, bhhb, xqf, xqb);
  k_lstm<<<32, 256, 0, stream>>>(wpk, xqf, xqb, hq, hx, flags);
  k_out<<<512, 256, 0, stream>>>(hq, Wo, bo, out);
}